// Round 5
// baseline (34.169 us; speedup 1.0000x reference)
//
#include <hip/hip_runtime.h>
#include <stdint.h>

// TripletLoss on MI355X. E=8192, N=2048, K=8, L=16, top-400 of Gumbel-perturbed logw.
// Round 5: ONE single-block kernel (launch overhead dominated round 4's 4-launch
// pipeline). Phases: keypoint mask -> per-edge argmax/bc/flags + packed pos|neg
// counts -> in-place packed scans (pos & neg bases in one int; pair-count scan)
// -> CSR fill -> one-thread-per-valid-pair (binary search over pair bases)
// -> 4-pass radix threshold (wave-0 shfl suffix scan) -> deterministic reduce.

#define E_CONST 8192
#define N_CONST 2048
#define K_CONST 8
#define L_CONST 16
#define MAXS 400
#define EPS_F 1e-9f
#define NTHR 1024

struct Cand { float val; uint32_t pack; };

// ---- threefry2x32, key = jax.random.key(42), partitionable path (validated absmax 0.0) ----
__device__ __forceinline__ uint2 threefry2x32_42(uint32_t x0, uint32_t x1) {
    const uint32_t ks0 = 0u, ks1 = 42u;
    const uint32_t ks2 = ks0 ^ ks1 ^ 0x1BD11BDAu;
    const uint32_t ks[3] = {ks0, ks1, ks2};
    const int R[2][4] = {{13, 15, 26, 6}, {17, 29, 16, 24}};
    x0 += ks0; x1 += ks1;
#pragma unroll
    for (int g = 0; g < 5; ++g) {
        const int* r = R[g & 1];
#pragma unroll
        for (int q = 0; q < 4; ++q) {
            x0 += x1;
            x1 = (x1 << r[q]) | (x1 >> (32 - r[q]));
            x1 ^= x0;
        }
        x0 += ks[(g + 1) % 3];
        x1 += ks[(g + 2) % 3] + (uint32_t)(g + 1);
    }
    return make_uint2(x0, x1);
}

__device__ __forceinline__ float gumbel_at(uint32_t idx) {
    uint2 o = threefry2x32_42(0u, idx);
    uint32_t bits = o.x ^ o.y;
    float u = __uint_as_float((bits >> 9) | 0x3F800000u) - 1.0f;
    return -logf(-logf(u + EPS_F) + EPS_F);
}

__device__ __forceinline__ uint32_t sortable_key(float f) {
    uint32_t b = __float_as_uint(f);
    return (b & 0x80000000u) ? ~b : (b | 0x80000000u);
}

__device__ __forceinline__ int argmax8(float4 a, float4 b) {
    float v[8] = {a.x, a.y, a.z, a.w, b.x, b.y, b.z, b.w};
    float best = v[0]; int bi = 0;
#pragma unroll
    for (int k = 1; k < 8; ++k)
        if (v[k] > best) { best = v[k]; bi = k; }  // first-max == jnp.argmax
    return bi;
}

// exclusive in-place scan of arr[2048] by 1024 threads (each owns 2 elems).
// Works for 16|16-bit packed fields: per-field totals < 65536 -> no cross-field carry.
__device__ __forceinline__ void scan_inplace(int* arr, int* tmp, int* totalOut) {
    int tid = threadIdx.x;
    int lane = tid & 63, wid = tid >> 6;
    int i0 = 2 * tid, i1 = i0 + 1;
    int v0 = arr[i0], v1 = arr[i1];
    int s = v0 + v1;
    int inc = s;
#pragma unroll
    for (int off = 1; off < 64; off <<= 1) {
        int u = __shfl_up(inc, off);
        if (lane >= off) inc += u;
    }
    if (lane == 63) tmp[wid] = inc;
    __syncthreads();
    if (wid == 0) {
        int w = (lane < 16) ? tmp[lane] : 0;
        int incw = w;
#pragma unroll
        for (int off = 1; off < 16; off <<= 1) {
            int u = __shfl_up(incw, off);
            if (lane >= off) incw += u;
        }
        if (lane < 16) tmp[lane] = incw - w;  // exclusive wave bases
    }
    __syncthreads();
    int base = tmp[wid] + (inc - s);
    arr[i0] = base;
    arr[i1] = base + v0;
    if (tid == 1023) *totalOut = base + v0 + v1;
    __syncthreads();
}

__global__ __launch_bounds__(1024) void k_all(
    const float* __restrict__ probas, const float* __restrict__ clusters,
    const int* __restrict__ edges, const int* __restrict__ keypts,
    float* __restrict__ bc, Cand* __restrict__ cand, int pmax,
    float* __restrict__ out) {

    __shared__ int s_pk[N_CONST];        // packed cnt (P low16 | N high16) -> packed base
    __shared__ int s_q[N_CONST];         // pair cnt -> pair base
    __shared__ int s_cur[N_CONST];       // packed fill cursors
    __shared__ uint16_t s_csr[E_CONST];  // pos entries [0,nPosTot), neg at nPosTot+
    __shared__ int s_tmp[16];
    __shared__ int s_hist[256];
    __shared__ float s_wsum[16];
    __shared__ int s_wcnt[16];
    __shared__ uint32_t s_mask;
    __shared__ int s_totPk, s_totQ;
    __shared__ uint32_t s_prefix;
    __shared__ int s_target;

    int tid = threadIdx.x;
    s_pk[2 * tid] = 0; s_pk[2 * tid + 1] = 0;
    if (tid == 0) s_mask = 0;
    __syncthreads();

    // phase 0: keypoint cluster mask
    if (tid < L_CONST) {
        const float4* r = (const float4*)(clusters + keypts[tid] * K_CONST);
        atomicOr(&s_mask, 1u << argmax8(r[0], r[1]));
    }
    __syncthreads();
    uint32_t m = s_mask;

    // phase A: per-edge argmax both endpoints, bc, flags, packed counts
    const int2* ed2 = (const int2*)edges;
    const float4* c4 = (const float4*)clusters;
    uint32_t af[8];  // anchor(<<2) | flag
#pragma unroll
    for (int it = 0; it < 8; ++it) {
        int e = tid + it * NTHR;
        int2 p = ed2[e];
        float4 a0 = c4[2 * p.x], a1 = c4[2 * p.x + 1];
        float4 b0 = c4[2 * p.y], b1 = c4[2 * p.y + 1];
        int c0 = argmax8(a0, a1);
        int c1 = argmax8(b0, b1);
        float s = sqrtf(a0.x * b0.x);       // k ascending, matches ref reduce order
        s += sqrtf(a0.y * b0.y);
        s += sqrtf(a0.z * b0.z);
        s += sqrtf(a0.w * b0.w);
        s += sqrtf(a1.x * b1.x);
        s += sqrtf(a1.y * b1.y);
        s += sqrtf(a1.z * b1.z);
        s += sqrtf(a1.w * b1.w);
        bc[e] = s;
        int f = 0;
        if ((((m >> c0) | (m >> c1)) & 1u)) f = (c0 == c1) ? 1 : 2;  // 1=pos, 2=neg
        af[it] = ((uint32_t)p.x << 2) | (uint32_t)f;
        if (f == 1)      atomicAdd(&s_pk[p.x], 1);
        else if (f == 2) atomicAdd(&s_pk[p.x], 0x10000);
    }
    __syncthreads();

    // phase B: pair counts, then scans (in-place)
    {
        int i0 = 2 * tid, i1 = i0 + 1;
        int p0 = s_pk[i0], p1 = s_pk[i1];
        s_q[i0] = (p0 & 0xFFFF) * (p0 >> 16);
        s_q[i1] = (p1 & 0xFFFF) * (p1 >> 16);
    }
    __syncthreads();
    scan_inplace(s_pk, s_tmp, &s_totPk);
    scan_inplace(s_q, s_tmp, &s_totQ);
    s_cur[2 * tid] = s_pk[2 * tid];
    s_cur[2 * tid + 1] = s_pk[2 * tid + 1];
    __syncthreads();
    int nPosTot = s_totPk & 0xFFFF;
    int nNegTot = s_totPk >> 16;
    int P = s_totQ; if (P > pmax) P = pmax;

    // phase C: CSR fill (packed cursors; pos in low16, neg in high16)
#pragma unroll
    for (int it = 0; it < 8; ++it) {
        int f = (int)(af[it] & 3u);
        int a = (int)(af[it] >> 2);
        int e = tid + it * NTHR;
        if (f == 1) {
            int old = atomicAdd(&s_cur[a], 1);
            s_csr[old & 0xFFFF] = (uint16_t)e;
        } else if (f == 2) {
            int old = atomicAdd(&s_cur[a], 0x10000);
            s_csr[nPosTot + (old >> 16)] = (uint16_t)e;
        }
    }
    __syncthreads();

    // phase D: one thread per valid pair
    for (int t = tid; t < P; t += NTHR) {
        int lo = 0, hi = N_CONST - 1;
#pragma unroll
        for (int itr = 0; itr < 11; ++itr) {  // largest a with s_q[a] <= t
            int mid = (lo + hi + 1) >> 1;
            if (s_q[mid] <= t) lo = mid; else hi = mid - 1;
        }
        int a = lo;
        int loc = t - s_q[a];
        int pk = s_pk[a];
        int pb = pk & 0xFFFF, nb = pk >> 16;
        int nextN = (a < N_CONST - 1) ? (s_pk[a + 1] >> 16) : nNegTot;
        int nn = nextN - nb;  // >= 1 for any anchor owning pairs
        int ip = loc / nn;
        int jn = loc - ip * nn;
        int i = s_csr[pb + ip];
        int j = s_csr[nPosTot + nb + jn];
        float w = 1.0f - 0.5f * (bc[i] + bc[j]);
        float val = (w > 0.0f)
            ? logf(fmaxf(w, EPS_F)) + gumbel_at((uint32_t)i * E_CONST + (uint32_t)j)
            : -INFINITY;  // ref: logw=-inf -> excluded via ok mask
        cand[t].val = val;
        cand[t].pack = ((uint32_t)i << 16) | (uint32_t)j;
    }
    __syncthreads();

    // phase E: 4-pass radix threshold (wave-0 shfl suffix-scan bin select)
    int M = P;
    uint32_t thr = 0;
    if (M > MAXS) {
        if (tid == 0) { s_prefix = 0; s_target = MAXS; }
        __syncthreads();
        for (int pass = 0; pass < 4; ++pass) {
            int shift = 24 - 8 * pass;
            if (tid < 256) s_hist[tid] = 0;
            __syncthreads();
            uint32_t pfx = s_prefix;
            for (int t = tid; t < M; t += NTHR) {
                uint32_t k = sortable_key(cand[t].val);
                if (pass == 0 || (k >> (shift + 8)) == pfx)
                    atomicAdd(&s_hist[(k >> shift) & 255], 1);
            }
            __syncthreads();
            if (tid < 64) {  // lane L owns bins 4L..4L+3
                int h0 = s_hist[4 * tid], h1 = s_hist[4 * tid + 1];
                int h2 = s_hist[4 * tid + 2], h3 = s_hist[4 * tid + 3];
                int sincl = h0 + h1 + h2 + h3;
#pragma unroll
                for (int off = 1; off < 64; off <<= 1) {
                    int v = __shfl_down(sincl, off);
                    if (tid + off < 64) sincl += v;
                }
                int excl = __shfl_down(sincl, 1);
                if (tid == 63) excl = 0;
                int suf3 = excl + h3;
                int suf2 = suf3 + h2;
                int suf1 = suf2 + h1;
                int suf0 = suf1 + h0;
                int tgt = s_target;
                uint32_t pfxOld = s_prefix;
                if      (suf0 >= tgt && suf1 < tgt) { s_prefix = (pfxOld << 8) | (4u*tid+0); s_target = tgt - suf1; }
                else if (suf1 >= tgt && suf2 < tgt) { s_prefix = (pfxOld << 8) | (4u*tid+1); s_target = tgt - suf2; }
                else if (suf2 >= tgt && suf3 < tgt) { s_prefix = (pfxOld << 8) | (4u*tid+2); s_target = tgt - suf3; }
                else if (suf3 >= tgt && excl < tgt) { s_prefix = (pfxOld << 8) | (4u*tid+3); s_target = tgt - excl; }
            }
            __syncthreads();
        }
        thr = s_prefix;  // exact sortable key of the 400th-largest value
    }

    // phase F: deterministic reduce of selected terms
    float mysum = 0.f;
    int myc = 0;
    for (int t = tid; t < M; t += NTHR) {
        Cand c = cand[t];
        if (c.val != -INFINITY && sortable_key(c.val) >= thr) {
            int i = (int)(c.pack >> 16), j = (int)(c.pack & 0xFFFFu);
            float pi = probas[i], pj = probas[j];
            mysum += logf(pi / (pi + pj));
            myc++;
        }
    }
#pragma unroll
    for (int off = 32; off > 0; off >>= 1) {
        mysum += __shfl_down(mysum, off);
        myc   += __shfl_down(myc, off);
    }
    int wid = tid >> 6;
    if ((tid & 63) == 0) { s_wsum[wid] = mysum; s_wcnt[wid] = myc; }
    __syncthreads();
    if (tid == 0) {
        float s = 0.f; int c = 0;
        for (int w = 0; w < 16; ++w) { s += s_wsum[w]; c += s_wcnt[w]; }
        if (c < 1) c = 1;
        out[0] = -s / (float)c;
    }
}

extern "C" void kernel_launch(void* const* d_in, const int* in_sizes, int n_in,
                              void* d_out, int out_size, void* d_ws, size_t ws_size,
                              hipStream_t stream) {
    const float* probas   = (const float*)d_in[0];
    const float* clusters = (const float*)d_in[1];
    const int*   edges    = (const int*)d_in[2];
    const int*   keypts   = (const int*)d_in[3];
    float* out = (float*)d_out;

    char* ws = (char*)d_ws;
    float* bc   = (float*)(ws);           // 32768 B
    Cand*  cand = (Cand*)(ws + 33024);    // 8 B per pair
    long long avail = (long long)ws_size - 33024;
    int pmax = (avail > 0) ? (int)(avail / 8) : 0;
    if (pmax > 65536) pmax = 65536;

    k_all<<<1, 1024, 0, stream>>>(probas, clusters, edges, keypts, bc, cand, pmax, out);
}

// Round 6
// 28.667 us; speedup vs baseline: 1.1919x; 1.1919x over previous
//
#include <hip/hip_runtime.h>
#include <stdint.h>

// TripletLoss on MI355X. E=8192, N=2048, K=8, L=16, top-400 of Gumbel-perturbed logw.
// Round 6: two kernels. k_prep (64 blk x 128): the gather-heavy per-edge phase
// (random cluster-row reads need many CUs' L1 paths — round 5 proved 1 CU = 50us).
// k_fused (1 blk x 1024): dense pipeline validated in round 5 — packed counts ->
// in-place packed scans -> CSR fill -> one-thread-per-pair (binary search) ->
// 4-pass radix threshold (wave-0 shfl suffix scan) -> deterministic reduce.

#define E_CONST 8192
#define N_CONST 2048
#define K_CONST 8
#define L_CONST 16
#define MAXS 400
#define EPS_F 1e-9f
#define NTHR 1024

struct Cand { float val; uint32_t pack; };

// ---- threefry2x32, key = jax.random.key(42), partitionable path (validated absmax 0.0) ----
__device__ __forceinline__ uint2 threefry2x32_42(uint32_t x0, uint32_t x1) {
    const uint32_t ks0 = 0u, ks1 = 42u;
    const uint32_t ks2 = ks0 ^ ks1 ^ 0x1BD11BDAu;
    const uint32_t ks[3] = {ks0, ks1, ks2};
    const int R[2][4] = {{13, 15, 26, 6}, {17, 29, 16, 24}};
    x0 += ks0; x1 += ks1;
#pragma unroll
    for (int g = 0; g < 5; ++g) {
        const int* r = R[g & 1];
#pragma unroll
        for (int q = 0; q < 4; ++q) {
            x0 += x1;
            x1 = (x1 << r[q]) | (x1 >> (32 - r[q]));
            x1 ^= x0;
        }
        x0 += ks[(g + 1) % 3];
        x1 += ks[(g + 2) % 3] + (uint32_t)(g + 1);
    }
    return make_uint2(x0, x1);
}

__device__ __forceinline__ float gumbel_at(uint32_t idx) {
    uint2 o = threefry2x32_42(0u, idx);
    uint32_t bits = o.x ^ o.y;
    float u = __uint_as_float((bits >> 9) | 0x3F800000u) - 1.0f;
    return -logf(-logf(u + EPS_F) + EPS_F);
}

__device__ __forceinline__ uint32_t sortable_key(float f) {
    uint32_t b = __float_as_uint(f);
    return (b & 0x80000000u) ? ~b : (b | 0x80000000u);
}

__device__ __forceinline__ int argmax8(float4 a, float4 b) {
    float v[8] = {a.x, a.y, a.z, a.w, b.x, b.y, b.z, b.w};
    float best = v[0]; int bi = 0;
#pragma unroll
    for (int k = 1; k < 8; ++k)
        if (v[k] > best) { best = v[k]; bi = k; }  // first-max == jnp.argmax
    return bi;
}

// ---- kernel 1 (64 blocks x 128): gather-heavy per-edge bc + flags ----
__global__ __launch_bounds__(128) void k_prep(
    const float* __restrict__ clusters, const int* __restrict__ edges,
    const int* __restrict__ keypts,
    float* __restrict__ bc, unsigned char* __restrict__ flags) {
    __shared__ uint32_t s_mask;
    int tid = threadIdx.x;
    if (tid == 0) s_mask = 0;
    __syncthreads();
    if (tid < L_CONST) {
        const float4* r = (const float4*)(clusters + keypts[tid] * K_CONST);
        atomicOr(&s_mask, 1u << argmax8(r[0], r[1]));
    }
    __syncthreads();
    uint32_t m = s_mask;

    int e = blockIdx.x * 128 + tid;  // grid == E exactly
    const int2* ed2 = (const int2*)edges;
    const float4* c4 = (const float4*)clusters;
    int2 p = ed2[e];
    float4 a0 = c4[2 * p.x], a1 = c4[2 * p.x + 1];
    float4 b0 = c4[2 * p.y], b1 = c4[2 * p.y + 1];
    int c0 = argmax8(a0, a1);
    int c1 = argmax8(b0, b1);
    float s = sqrtf(a0.x * b0.x);       // k ascending, matches ref reduce order
    s += sqrtf(a0.y * b0.y);
    s += sqrtf(a0.z * b0.z);
    s += sqrtf(a0.w * b0.w);
    s += sqrtf(a1.x * b1.x);
    s += sqrtf(a1.y * b1.y);
    s += sqrtf(a1.z * b1.z);
    s += sqrtf(a1.w * b1.w);
    bc[e] = s;
    unsigned char f = 0;
    if ((((m >> c0) | (m >> c1)) & 1u)) f = (c0 == c1) ? 1 : 2;  // 1=pos, 2=neg
    flags[e] = f;
}

// exclusive in-place scan of arr[2048] by 1024 threads (each owns 2 elems).
// Works for 16|16-bit packed fields: per-field totals < 65536 -> no cross-field carry.
__device__ __forceinline__ void scan_inplace(int* arr, int* tmp, int* totalOut) {
    int tid = threadIdx.x;
    int lane = tid & 63, wid = tid >> 6;
    int i0 = 2 * tid, i1 = i0 + 1;
    int v0 = arr[i0], v1 = arr[i1];
    int s = v0 + v1;
    int inc = s;
#pragma unroll
    for (int off = 1; off < 64; off <<= 1) {
        int u = __shfl_up(inc, off);
        if (lane >= off) inc += u;
    }
    if (lane == 63) tmp[wid] = inc;
    __syncthreads();
    if (wid == 0) {
        int w = (lane < 16) ? tmp[lane] : 0;
        int incw = w;
#pragma unroll
        for (int off = 1; off < 16; off <<= 1) {
            int u = __shfl_up(incw, off);
            if (lane >= off) incw += u;
        }
        if (lane < 16) tmp[lane] = incw - w;  // exclusive wave bases
    }
    __syncthreads();
    int base = tmp[wid] + (inc - s);
    arr[i0] = base;
    arr[i1] = base + v0;
    if (tid == 1023) *totalOut = base + v0 + v1;
    __syncthreads();
}

// ---- kernel 2 (1 block x 1024): scans + CSR + pairs + radix top-k + reduce ----
__global__ __launch_bounds__(1024) void k_fused(
    const float* __restrict__ probas, const int* __restrict__ edges,
    const unsigned char* __restrict__ flags, const float* __restrict__ bc,
    Cand* __restrict__ cand, int pmax, float* __restrict__ out) {

    __shared__ int s_pk[N_CONST];        // packed cnt (P low16 | N high16) -> packed base
    __shared__ int s_q[N_CONST];         // pair cnt -> pair base
    __shared__ int s_cur[N_CONST];       // packed fill cursors
    __shared__ uint16_t s_csr[E_CONST];  // pos entries [0,nPosTot), neg at nPosTot+
    __shared__ int s_tmp[16];
    __shared__ int s_hist[256];
    __shared__ float s_wsum[16];
    __shared__ int s_wcnt[16];
    __shared__ int s_totPk, s_totQ;
    __shared__ uint32_t s_prefix;
    __shared__ int s_target;

    int tid = threadIdx.x;
    s_pk[2 * tid] = 0; s_pk[2 * tid + 1] = 0;
    __syncthreads();

    // phase B0: reload per-edge anchor+flag (coalesced), packed counts
    const int2* ed2 = (const int2*)edges;
    uint32_t af[8];  // anchor(<<2) | flag
#pragma unroll
    for (int it = 0; it < 8; ++it) {
        int e = tid + it * NTHR;
        int a = ed2[e].x;
        int f = flags[e];
        af[it] = ((uint32_t)a << 2) | (uint32_t)f;
        if (f == 1)      atomicAdd(&s_pk[a], 1);
        else if (f == 2) atomicAdd(&s_pk[a], 0x10000);
    }
    __syncthreads();

    // phase B: pair counts, then scans (in-place)
    {
        int i0 = 2 * tid, i1 = i0 + 1;
        int p0 = s_pk[i0], p1 = s_pk[i1];
        s_q[i0] = (p0 & 0xFFFF) * (p0 >> 16);
        s_q[i1] = (p1 & 0xFFFF) * (p1 >> 16);
    }
    __syncthreads();
    scan_inplace(s_pk, s_tmp, &s_totPk);
    scan_inplace(s_q, s_tmp, &s_totQ);
    s_cur[2 * tid] = s_pk[2 * tid];
    s_cur[2 * tid + 1] = s_pk[2 * tid + 1];
    __syncthreads();
    int nPosTot = s_totPk & 0xFFFF;
    int nNegTot = s_totPk >> 16;
    int P = s_totQ; if (P > pmax) P = pmax;

    // phase C: CSR fill (packed cursors; pos in low16, neg in high16)
#pragma unroll
    for (int it = 0; it < 8; ++it) {
        int f = (int)(af[it] & 3u);
        int a = (int)(af[it] >> 2);
        int e = tid + it * NTHR;
        if (f == 1) {
            int old = atomicAdd(&s_cur[a], 1);
            s_csr[old & 0xFFFF] = (uint16_t)e;
        } else if (f == 2) {
            int old = atomicAdd(&s_cur[a], 0x10000);
            s_csr[nPosTot + (old >> 16)] = (uint16_t)e;
        }
    }
    __syncthreads();

    // phase D: one thread per valid pair
    for (int t = tid; t < P; t += NTHR) {
        int lo = 0, hi = N_CONST - 1;
#pragma unroll
        for (int itr = 0; itr < 11; ++itr) {  // largest a with s_q[a] <= t
            int mid = (lo + hi + 1) >> 1;
            if (s_q[mid] <= t) lo = mid; else hi = mid - 1;
        }
        int a = lo;
        int loc = t - s_q[a];
        int pk = s_pk[a];
        int pb = pk & 0xFFFF, nb = pk >> 16;
        int nextN = (a < N_CONST - 1) ? (s_pk[a + 1] >> 16) : nNegTot;
        int nn = nextN - nb;  // >= 1 for any anchor owning pairs
        int ip = loc / nn;
        int jn = loc - ip * nn;
        int i = s_csr[pb + ip];
        int j = s_csr[nPosTot + nb + jn];
        float w = 1.0f - 0.5f * (bc[i] + bc[j]);
        float val = (w > 0.0f)
            ? logf(fmaxf(w, EPS_F)) + gumbel_at((uint32_t)i * E_CONST + (uint32_t)j)
            : -INFINITY;  // ref: logw=-inf -> excluded via ok mask
        cand[t].val = val;
        cand[t].pack = ((uint32_t)i << 16) | (uint32_t)j;
    }
    __syncthreads();

    // phase E: 4-pass radix threshold (wave-0 shfl suffix-scan bin select)
    int M = P;
    uint32_t thr = 0;
    if (M > MAXS) {
        if (tid == 0) { s_prefix = 0; s_target = MAXS; }
        __syncthreads();
        for (int pass = 0; pass < 4; ++pass) {
            int shift = 24 - 8 * pass;
            if (tid < 256) s_hist[tid] = 0;
            __syncthreads();
            uint32_t pfx = s_prefix;
            for (int t = tid; t < M; t += NTHR) {
                uint32_t k = sortable_key(cand[t].val);
                if (pass == 0 || (k >> (shift + 8)) == pfx)
                    atomicAdd(&s_hist[(k >> shift) & 255], 1);
            }
            __syncthreads();
            if (tid < 64) {  // lane L owns bins 4L..4L+3
                int h0 = s_hist[4 * tid], h1 = s_hist[4 * tid + 1];
                int h2 = s_hist[4 * tid + 2], h3 = s_hist[4 * tid + 3];
                int sincl = h0 + h1 + h2 + h3;
#pragma unroll
                for (int off = 1; off < 64; off <<= 1) {
                    int v = __shfl_down(sincl, off);
                    if (tid + off < 64) sincl += v;
                }
                int excl = __shfl_down(sincl, 1);
                if (tid == 63) excl = 0;
                int suf3 = excl + h3;
                int suf2 = suf3 + h2;
                int suf1 = suf2 + h1;
                int suf0 = suf1 + h0;
                int tgt = s_target;
                uint32_t pfxOld = s_prefix;
                if      (suf0 >= tgt && suf1 < tgt) { s_prefix = (pfxOld << 8) | (4u*tid+0); s_target = tgt - suf1; }
                else if (suf1 >= tgt && suf2 < tgt) { s_prefix = (pfxOld << 8) | (4u*tid+1); s_target = tgt - suf2; }
                else if (suf2 >= tgt && suf3 < tgt) { s_prefix = (pfxOld << 8) | (4u*tid+2); s_target = tgt - suf3; }
                else if (suf3 >= tgt && excl < tgt) { s_prefix = (pfxOld << 8) | (4u*tid+3); s_target = tgt - excl; }
            }
            __syncthreads();
        }
        thr = s_prefix;  // exact sortable key of the 400th-largest value
    }

    // phase F: deterministic reduce of selected terms
    float mysum = 0.f;
    int myc = 0;
    for (int t = tid; t < M; t += NTHR) {
        Cand c = cand[t];
        if (c.val != -INFINITY && sortable_key(c.val) >= thr) {
            int i = (int)(c.pack >> 16), j = (int)(c.pack & 0xFFFFu);
            float pi = probas[i], pj = probas[j];
            mysum += logf(pi / (pi + pj));
            myc++;
        }
    }
#pragma unroll
    for (int off = 32; off > 0; off >>= 1) {
        mysum += __shfl_down(mysum, off);
        myc   += __shfl_down(myc, off);
    }
    int wid = tid >> 6;
    if ((tid & 63) == 0) { s_wsum[wid] = mysum; s_wcnt[wid] = myc; }
    __syncthreads();
    if (tid == 0) {
        float s = 0.f; int c = 0;
        for (int w = 0; w < 16; ++w) { s += s_wsum[w]; c += s_wcnt[w]; }
        if (c < 1) c = 1;
        out[0] = -s / (float)c;
    }
}

extern "C" void kernel_launch(void* const* d_in, const int* in_sizes, int n_in,
                              void* d_out, int out_size, void* d_ws, size_t ws_size,
                              hipStream_t stream) {
    const float* probas   = (const float*)d_in[0];
    const float* clusters = (const float*)d_in[1];
    const int*   edges    = (const int*)d_in[2];
    const int*   keypts   = (const int*)d_in[3];
    float* out = (float*)d_out;

    char* ws = (char*)d_ws;
    float*         bc    = (float*)(ws);                  // 32768 B
    unsigned char* flags = (unsigned char*)(ws + 32768);  // 8192 B
    Cand*          cand  = (Cand*)(ws + 40960);           // 8 B per pair
    long long avail = (long long)ws_size - 40960;
    int pmax = (avail > 0) ? (int)(avail / 8) : 0;
    if (pmax > 65536) pmax = 65536;

    k_prep <<<64, 128, 0, stream>>>(clusters, edges, keypts, bc, flags);
    k_fused<<<1, 1024, 0, stream>>>(probas, edges, flags, bc, cand, pmax, out);
}